// Round 2
// baseline (183.152 us; speedup 1.0000x reference)
//
#include <hip/hip_runtime.h>
#include <hip/hip_cooperative_groups.h>
#include <stdint.h>

#define NB 4096          // number of boxes
#define NBLK 64          // 64 blocks of 64 boxes
#define LLOC 16384       // number of locations
#define IOU_THR 0.5f
#define ECAP 1024        // entry capacity per source block bucket
#define RANKB 256        // rank blocks (16 boxes each) -- legacy path
#define NTRI (NBLK * (NBLK + 1) / 2)   // 2080 upper-triangle tiles
#define GRID 256         // cooperative grid: 1 block/CU guaranteed resident

namespace cg = cooperative_groups;
typedef unsigned long long u64;

__device__ __forceinline__ u64 readlane64(u64 v, int lane) {
    unsigned lo = (unsigned)__builtin_amdgcn_readlane((int)(unsigned)(v & 0xffffffffull), lane);
    unsigned hi = (unsigned)__builtin_amdgcn_readlane((int)(unsigned)(v >> 32), lane);
    return ((u64)hi << 32) | (u64)lo;
}

// ===========================================================================
// Single cooperative kernel: P0 front -> sync -> P1 edges -> sync -> P2 scan.
// Replaces 3 dependent dispatches (and their launch gaps) with 1.
// ===========================================================================
__global__ void __launch_bounds__(256) fcos_fused(
        const float* __restrict__ boxes, const float* __restrict__ scores,
        const int* __restrict__ cls, const float* __restrict__ loc,
        const float* __restrict__ deltas, const int* __restrict__ stride_p,
        float* __restrict__ keep_out, float* __restrict__ pred_out,
        float* __restrict__ maxc, int* __restrict__ sidx,
        int* __restrict__ counts, uint4* __restrict__ entries,
        u64* __restrict__ dcol) {
    __shared__ __align__(16) float sh[NB];       // 16 KB: rank scores
    __shared__ float4 cbs[4][64];                // 4 KB: per-wave edge col tiles
    __shared__ float cas[4][64];                 // 1 KB
    __shared__ u64 rem_lds[NBLK];                // scan removed-mask
    __shared__ u64 kept_lds[NBLK];               // scan kept-mask
    __shared__ float red[4];

    cg::grid_group gridg = cg::this_grid();
    const int blk = blockIdx.x;
    const int t = threadIdx.x;
    const int wave = t >> 6, lane = t & 63;

    // ---------------- P0a: pred boxes + centerness (blocks 0-63) ------------
    if (blk < 64) {
        int i = blk * 256 + t;
        float s = (float)stride_p[0];
        float2 p = ((const float2*)loc)[i];
        float4 d = ((const float4*)deltas)[i];
        float c0 = fmaxf(d.x, 0.f), c1 = fmaxf(d.y, 0.f);
        float c2 = fmaxf(d.z, 0.f), c3 = fmaxf(d.w, 0.f);
        float b0 = p.x - c0 * s;
        float b1 = p.y - c1 * s;
        float b2 = p.x + c2 * s;
        float b3 = p.y + c3 * s;
        float lr_min = fminf(d.x, d.z), tb_min = fminf(d.y, d.w);
        float lr_max = fmaxf(d.x, d.z), tb_max = fmaxf(d.y, d.w);
        float cent = sqrtf((lr_min * tb_min) / (lr_max * tb_max));
        if (d.x == -1.f && d.y == -1.f && d.z == -1.f && d.w == -1.f) cent = -1.f;
        float* o = pred_out + (size_t)i * 5;
        o[0] = b0; o[1] = b1; o[2] = b2; o[3] = b3; o[4] = cent;
    }
    // ---------------- P0b: max coordinate + zero counters (block 64) --------
    if (blk == 64) {
        if (t < NBLK) counts[t] = 0;
        float m = -3.0e38f;
        for (int i = t; i < NB * 4; i += 256) m = fmaxf(m, boxes[i]);
        for (int o = 32; o > 0; o >>= 1) m = fmaxf(m, __shfl_down(m, o));
        if ((t & 63) == 0) red[t >> 6] = m;
        __syncthreads();
        if (t == 0) *maxc = fmaxf(fmaxf(red[0], red[1]), fmaxf(red[2], red[3]));
    }
    // ---------------- P0c: rank (all blocks, 16 boxes each) -----------------
    {
        for (int i = t; i < NB; i += 256) sh[i] = scores[i];
        __syncthreads();
        int base = blk * 16 + wave * 4;            // 4 consecutive boxes/wave
        float my0 = sh[base + 0], my1 = sh[base + 1];
        float my2 = sh[base + 2], my3 = sh[base + 3];
        int c0 = 0, c1 = 0, c2 = 0, c3 = 0;
#pragma unroll 8
        for (int k = 0; k < 64; ++k) {
            int j = lane + k * 64;                 // 2-way LDS bank alias: free
            float sj = sh[j];
            c0 += (sj > my0) || (sj == my0 && j < base + 0);
            c1 += (sj > my1) || (sj == my1 && j < base + 1);
            c2 += (sj > my2) || (sj == my2 && j < base + 2);
            c3 += (sj > my3) || (sj == my3 && j < base + 3);
        }
        for (int o = 32; o > 0; o >>= 1) {
            c0 += __shfl_down(c0, o); c1 += __shfl_down(c1, o);
            c2 += __shfl_down(c2, o); c3 += __shfl_down(c3, o);
        }
        if (lane == 0) {
            sidx[c0] = base + 0; sidx[c1] = base + 1;
            sidx[c2] = base + 2; sidx[c3] = base + 3;
        }
    }

    gridg.sync();

    // ---------------- P1: suppression-edge extraction (all waves) -----------
    {
        float mc1 = maxc[0] + 1.0f;
        float4* cb = cbs[wave];
        float* ca = cas[wave];
        int wgid = blk * 4 + wave;                 // 1024 waves over 2080 tiles
        for (int tile = wgid; tile < NTRI; tile += GRID * 4) {
            int idx = tile, r = 0;
            while (idx >= NBLK - r) { idx -= NBLK - r; ++r; }
            int c = r + idx;

            // gather row-tile box (sorted order) for this lane
            int jr = sidx[r * 64 + lane];
            float offr = (float)cls[jr] * mc1;
            float4 rb = ((const float4*)boxes)[jr];
            rb.x += offr; rb.y += offr; rb.z += offr; rb.w += offr;
            float ra = (rb.z - rb.x) * (rb.w - rb.y);

            // column tile into wave-local LDS (in-order DS pipe: no barrier)
            if (c == r) {
                cb[lane] = rb; ca[lane] = ra;
            } else {
                int jc = sidx[c * 64 + lane];
                float offc = (float)cls[jc] * mc1;
                float4 b = ((const float4*)boxes)[jc];
                b.x += offc; b.y += offc; b.z += offc; b.w += offc;
                cb[lane] = b; ca[lane] = (b.z - b.x) * (b.w - b.y);
            }

            u64 w = 0;
#pragma unroll 8
            for (int j = 0; j < 64; ++j) {
                float4 b = cb[j];
                float xi = fminf(rb.z, b.z) - fmaxf(rb.x, b.x);
                float yi = fminf(rb.w, b.w) - fmaxf(rb.y, b.y);
                float inter = fmaxf(xi, 0.f) * fmaxf(yi, 0.f);
                float iou = inter / (ra + ca[j] - inter);
                w |= (u64)(iou > IOU_THR) << j;
            }
            if (c == r) {
                w &= ~(1ull << lane);              // drop self-overlap bit
                dcol[r * 64 + lane] = w;           // dense diagonal word
            } else if (w) {
                int slot = atomicAdd(&counts[r], 1);
                if (slot < ECAP)
                    entries[r * ECAP + slot] =
                        make_uint4((unsigned)(lane | (c << 8)), 0u,
                                   (unsigned)(w & 0xffffffffull), (unsigned)(w >> 32));
            }
        }
    }

    gridg.sync();

    // ---------------- P2: serial greedy scan (block 0 only) -----------------
    if (blk == 0) {
        if (t < 64) {
            rem_lds[t] = 0;
            int cnt_l = counts[t];
            u64 keptall_w = 0;
            u64 self = 1ull << t;
            uint4 cur = entries[t];                // depth-2 prefetch
            uint4 n1  = entries[ECAP + t];
            u64 cw_cur = dcol[t];
            u64 cw_n1  = dcol[64 + t];
            for (int b = 0; b < NBLK; ++b) {
                uint4 n2; u64 cw_n2;
                if (b < NBLK - 2) {
                    n2    = entries[(u64)(b + 2) * ECAP + t];
                    cw_n2 = dcol[(b + 2) * 64 + t];
                }
                int cnt = __builtin_amdgcn_readlane(cnt_l, b);
                if (cnt > ECAP) cnt = ECAP;

                u64 colw = self | cw_cur;          // dense diagonal table

                u64 rem = rem_lds[b];              // same-wave DS in-order
                u64 avail = ~rem;
                u64 edges = colw & avail & ~self;
                u64 involved = __ballot(edges != 0ull) & avail;
                u64 keptm = avail & ~involved;
                u64 sub = involved;
                while (sub) {
                    int i = (int)__builtin_ctzll(sub);   // highest score first
                    keptm |= 1ull << i;
                    u64 ci = readlane64(colw, i);
                    sub &= ~(ci | (1ull << i));
                }
                if (t == b) keptall_w = keptm;

                // lane-parallel merge: lane e holds entry e from prefetch
                if (t < cnt) {
                    int l = cur.x & 255, c = cur.x >> 8;
                    if ((keptm >> l) & 1ull)
                        atomicOr(&rem_lds[c], ((u64)cur.w << 32) | cur.z);
                }
                for (int e = 64; e < cnt; e += 64) {     // overflow (rare)
                    int ee = e + t;
                    if (ee < cnt) {
                        uint4 x = entries[(u64)b * ECAP + ee];
                        int l = x.x & 255, c = x.x >> 8;
                        if ((keptm >> l) & 1ull)
                            atomicOr(&rem_lds[c], ((u64)x.w << 32) | x.z);
                    }
                }
                cur = n1; n1 = n2; cw_cur = cw_n1; cw_n1 = cw_n2;
            }
            kept_lds[t] = keptall_w;
        }
        __syncthreads();
        // epilogue: 4 waves x 16 iterations, scattered stores via sorted index
#pragma unroll
        for (int k = 0; k < 16; ++k) {
            int bb = wave + k * 4;
            u64 kw = kept_lds[bb];
            int idx = sidx[bb * 64 + lane];
            keep_out[idx] = ((kw >> lane) & 1ull) ? 1.0f : 0.0f;
        }
    }
}

// ===========================================================================
// Legacy 3-kernel path (verified round-1 code) -- fallback if the cooperative
// launch is rejected (validation / capture-unsupported).
// ===========================================================================
__global__ void __launch_bounds__(256) fused_front(
        const float* __restrict__ boxes, const float* __restrict__ scores,
        const float* __restrict__ loc, const float* __restrict__ deltas,
        const int* __restrict__ stride_p,
        float* __restrict__ pred_out, float* __restrict__ maxc,
        int* __restrict__ sidx, int* __restrict__ counts) {
    __shared__ __align__(16) float sh[NB];
    __shared__ float red[4];
    int blk = blockIdx.x;
    int t = threadIdx.x;

    if (blk < 64) {
        int i = blk * 256 + t;
        float s = (float)stride_p[0];
        float2 p = ((const float2*)loc)[i];
        float4 d = ((const float4*)deltas)[i];
        float c0 = fmaxf(d.x, 0.f), c1 = fmaxf(d.y, 0.f);
        float c2 = fmaxf(d.z, 0.f), c3 = fmaxf(d.w, 0.f);
        float b0 = p.x - c0 * s;
        float b1 = p.y - c1 * s;
        float b2 = p.x + c2 * s;
        float b3 = p.y + c3 * s;
        float lr_min = fminf(d.x, d.z), tb_min = fminf(d.y, d.w);
        float lr_max = fmaxf(d.x, d.z), tb_max = fmaxf(d.y, d.w);
        float cent = sqrtf((lr_min * tb_min) / (lr_max * tb_max));
        if (d.x == -1.f && d.y == -1.f && d.z == -1.f && d.w == -1.f) cent = -1.f;
        float* o = pred_out + (size_t)i * 5;
        o[0] = b0; o[1] = b1; o[2] = b2; o[3] = b3; o[4] = cent;
    } else if (blk < 64 + RANKB) {
        for (int i = t; i < NB; i += 256) sh[i] = scores[i];
        __syncthreads();
        int wave = t >> 6, lane = t & 63;
        int base = (blk - 64) * 16 + wave * 4;
        float my0 = sh[base + 0], my1 = sh[base + 1];
        float my2 = sh[base + 2], my3 = sh[base + 3];
        int c0 = 0, c1 = 0, c2 = 0, c3 = 0;
#pragma unroll 8
        for (int k = 0; k < 64; ++k) {
            int j = lane + k * 64;
            float sj = sh[j];
            c0 += (sj > my0) || (sj == my0 && j < base + 0);
            c1 += (sj > my1) || (sj == my1 && j < base + 1);
            c2 += (sj > my2) || (sj == my2 && j < base + 2);
            c3 += (sj > my3) || (sj == my3 && j < base + 3);
        }
        for (int o = 32; o > 0; o >>= 1) {
            c0 += __shfl_down(c0, o); c1 += __shfl_down(c1, o);
            c2 += __shfl_down(c2, o); c3 += __shfl_down(c3, o);
        }
        if (lane == 0) {
            sidx[c0] = base + 0; sidx[c1] = base + 1;
            sidx[c2] = base + 2; sidx[c3] = base + 3;
        }
    } else {
        if (t < NBLK) counts[t] = 0;
        float m = -3.0e38f;
        for (int i = t; i < NB * 4; i += 256) m = fmaxf(m, boxes[i]);
        for (int o = 32; o > 0; o >>= 1) m = fmaxf(m, __shfl_down(m, o));
        if ((t & 63) == 0) red[t >> 6] = m;
        __syncthreads();
        if (t == 0) *maxc = fmaxf(fmaxf(red[0], red[1]), fmaxf(red[2], red[3]));
    }
}

__global__ void __launch_bounds__(64) edge_kernel(
        const float* __restrict__ boxes, const int* __restrict__ cls,
        const float* __restrict__ maxc, const int* __restrict__ sidx,
        int* __restrict__ counts, uint4* __restrict__ entries,
        u64* __restrict__ dcol) {
    int idx = blockIdx.x, r = 0;
    while (idx >= NBLK - r) { idx -= NBLK - r; ++r; }
    int c = r + idx;

    __shared__ float4 cb[64];
    __shared__ float ca[64];
    int t = threadIdx.x;
    float mc1 = maxc[0] + 1.0f;

    int jr = sidx[r * 64 + t];
    float offr = (float)cls[jr] * mc1;
    float4 rb = ((const float4*)boxes)[jr];
    rb.x += offr; rb.y += offr; rb.z += offr; rb.w += offr;
    float ra = (rb.z - rb.x) * (rb.w - rb.y);

    if (c == r) {
        cb[t] = rb; ca[t] = ra;
    } else {
        int jc = sidx[c * 64 + t];
        float offc = (float)cls[jc] * mc1;
        float4 b = ((const float4*)boxes)[jc];
        b.x += offc; b.y += offc; b.z += offc; b.w += offc;
        cb[t] = b; ca[t] = (b.z - b.x) * (b.w - b.y);
    }
    __syncthreads();

    u64 w = 0;
#pragma unroll 8
    for (int j = 0; j < 64; ++j) {
        float4 b = cb[j];
        float xi = fminf(rb.z, b.z) - fmaxf(rb.x, b.x);
        float yi = fminf(rb.w, b.w) - fmaxf(rb.y, b.y);
        float inter = fmaxf(xi, 0.f) * fmaxf(yi, 0.f);
        float iou = inter / (ra + ca[j] - inter);
        w |= (u64)(iou > IOU_THR) << j;
    }
    if (c == r) {
        w &= ~(1ull << t);
        dcol[r * 64 + t] = w;
    } else if (w) {
        int slot = atomicAdd(&counts[r], 1);
        if (slot < ECAP)
            entries[r * ECAP + slot] =
                make_uint4((unsigned)(t | (c << 8)), 0u,
                           (unsigned)(w & 0xffffffffull), (unsigned)(w >> 32));
    }
}

__global__ void __launch_bounds__(256) scan_kernel(
        const int* __restrict__ counts, const uint4* __restrict__ entries,
        const u64* __restrict__ dcol, const int* __restrict__ sidx,
        float* __restrict__ keep_out) {
    __shared__ u64 rem_lds[NBLK];
    __shared__ u64 kept_lds[NBLK];
    const int t = threadIdx.x;
    const int lane = t & 63;

    if (t < 64) {
        rem_lds[t] = 0;
        int cnt_l = counts[lane];
        u64 keptall_w = 0;
        u64 self = 1ull << lane;
        uint4 cur = entries[lane];
        uint4 n1  = entries[ECAP + lane];
        u64 cw_cur = dcol[lane];
        u64 cw_n1  = dcol[64 + lane];
        for (int b = 0; b < NBLK; ++b) {
            uint4 n2; u64 cw_n2;
            if (b < NBLK - 2) {
                n2    = entries[(u64)(b + 2) * ECAP + lane];
                cw_n2 = dcol[(b + 2) * 64 + lane];
            }
            int cnt = __builtin_amdgcn_readlane(cnt_l, b);
            if (cnt > ECAP) cnt = ECAP;
            u64 colw = self | cw_cur;
            u64 rem = rem_lds[b];
            u64 avail = ~rem;
            u64 edges = colw & avail & ~self;
            u64 involved = __ballot(edges != 0ull) & avail;
            u64 keptm = avail & ~involved;
            u64 sub = involved;
            while (sub) {
                int i = (int)__builtin_ctzll(sub);
                keptm |= 1ull << i;
                u64 ci = readlane64(colw, i);
                sub &= ~(ci | (1ull << i));
            }
            if (lane == b) keptall_w = keptm;
            if (lane < cnt) {
                int l = cur.x & 255, c = cur.x >> 8;
                if ((keptm >> l) & 1ull)
                    atomicOr(&rem_lds[c], ((u64)cur.w << 32) | cur.z);
            }
            for (int e = 64; e < cnt; e += 64) {
                int ee = e + lane;
                if (ee < cnt) {
                    uint4 x = entries[(u64)b * ECAP + ee];
                    int l = x.x & 255, c = x.x >> 8;
                    if ((keptm >> l) & 1ull)
                        atomicOr(&rem_lds[c], ((u64)x.w << 32) | x.z);
                }
            }
            cur = n1; n1 = n2; cw_cur = cw_n1; cw_n1 = cw_n2;
        }
        kept_lds[lane] = keptall_w;
    }
    __syncthreads();

    int w = t >> 6;
#pragma unroll
    for (int k = 0; k < 16; ++k) {
        int bb = w + k * 4;
        u64 kw = kept_lds[bb];
        int idx = sidx[bb * 64 + lane];
        keep_out[idx] = ((kw >> lane) & 1ull) ? 1.0f : 0.0f;
    }
}

extern "C" void kernel_launch(void* const* d_in, const int* in_sizes, int n_in,
                              void* d_out, int out_size, void* d_ws, size_t ws_size,
                              hipStream_t stream) {
    const float* boxes   = (const float*)d_in[0];   // (4096,4)
    const float* scores  = (const float*)d_in[1];   // (4096,)
    const int*   cls     = (const int*)d_in[2];     // (4096,)
    const float* loc     = (const float*)d_in[3];   // (16384,2)
    const float* deltas  = (const float*)d_in[4];   // (16384,4)
    const int*   stride  = (const int*)d_in[5];     // scalar

    float* out = (float*)d_out;
    float* keep_out = out;          // 4096 floats (bool as 0/1)
    float* pred_out = out + NB;     // 16384*5 floats

    // workspace layout (16B-aligned pieces), ~1.08 MiB total
    char* ws = (char*)d_ws;
    float* maxc    = (float*)ws;                     ws += 16;
    int*   sidx    = (int*)ws;                       ws += NB * sizeof(int);
    int*   counts  = (int*)ws;                       ws += NBLK * sizeof(int) + 16;
    uint4* entries = (uint4*)ws;                     ws += (size_t)NBLK * ECAP * sizeof(uint4);
    u64*   dcol    = (u64*)ws;                       // NBLK*64*8 B = 32 KiB

    void* args[] = {(void*)&boxes, (void*)&scores, (void*)&cls, (void*)&loc,
                    (void*)&deltas, (void*)&stride, (void*)&keep_out,
                    (void*)&pred_out, (void*)&maxc, (void*)&sidx,
                    (void*)&counts, (void*)&entries, (void*)&dcol};
    hipError_t err = hipLaunchCooperativeKernel((const void*)fcos_fused,
                                                dim3(GRID), dim3(256),
                                                args, 0, stream);
    if (err != hipSuccess) {
        // fallback: verified 3-kernel path
        fused_front<<<64 + RANKB + 1, 256, 0, stream>>>(boxes, scores, loc, deltas,
                                                        stride, pred_out, maxc, sidx, counts);
        edge_kernel<<<NTRI, 64, 0, stream>>>(boxes, cls, maxc, sidx, counts, entries, dcol);
        scan_kernel<<<1, 256, 0, stream>>>(counts, entries, dcol, sidx, keep_out);
    }
}

// Round 3
// 116.053 us; speedup vs baseline: 1.5782x; 1.5782x over previous
//
#include <hip/hip_runtime.h>
#include <stdint.h>

#define NB 4096          // number of boxes
#define NBLK 64          // 64 blocks of 64 boxes
#define LLOC 16384       // number of locations
#define IOU_THR 0.5f
#define ECAP 1024        // entry capacity per source block bucket
#define RANKB 256        // rank blocks (16 boxes each)
#define NTRI (NBLK * (NBLK + 1) / 2)   // 2080 upper-triangle tiles
#define EBLK 520         // edge blocks: 4 waves x 1 tile each = 2080 tiles
#define PREDB 64         // pred blocks appended to edge kernel

typedef unsigned long long u64;

__device__ __forceinline__ u64 readlane64(u64 v, int lane) {
    unsigned lo = (unsigned)__builtin_amdgcn_readlane((int)(unsigned)(v & 0xffffffffull), lane);
    unsigned hi = (unsigned)__builtin_amdgcn_readlane((int)(unsigned)(v >> 32), lane);
    return ((u64)hi << 32) | (u64)lo;
}

// ------- front: rank (blocks 0-255, wave-per-4-boxes), maxc+zero (block 256) -
__global__ void __launch_bounds__(256) front_kernel(
        const float* __restrict__ boxes, const float* __restrict__ scores,
        float* __restrict__ maxc, int* __restrict__ sidx,
        int* __restrict__ counts /* counts[NBLK] then done at counts[NBLK] */) {
    __shared__ __align__(16) float sh[NB];
    __shared__ float red[4];
    int blk = blockIdx.x;
    int t = threadIdx.x;

    if (blk < RANKB) {
        // ---- rank: one wave per 4 boxes, 64-iteration j-loop ----
        for (int i = t; i < NB; i += 256) sh[i] = scores[i];
        __syncthreads();
        int wave = t >> 6, lane = t & 63;
        int base = blk * 16 + wave * 4;            // 4 consecutive boxes
        float my0 = sh[base + 0], my1 = sh[base + 1];
        float my2 = sh[base + 2], my3 = sh[base + 3];
        int c0 = 0, c1 = 0, c2 = 0, c3 = 0;
#pragma unroll 8
        for (int k = 0; k < 64; ++k) {
            int j = lane + k * 64;                 // 2-way LDS bank alias: free
            float sj = sh[j];
            c0 += (sj > my0) || (sj == my0 && j < base + 0);
            c1 += (sj > my1) || (sj == my1 && j < base + 1);
            c2 += (sj > my2) || (sj == my2 && j < base + 2);
            c3 += (sj > my3) || (sj == my3 && j < base + 3);
        }
        for (int o = 32; o > 0; o >>= 1) {
            c0 += __shfl_down(c0, o); c1 += __shfl_down(c1, o);
            c2 += __shfl_down(c2, o); c3 += __shfl_down(c3, o);
        }
        if (lane == 0) {
            sidx[c0] = base + 0; sidx[c1] = base + 1;
            sidx[c2] = base + 2; sidx[c3] = base + 3;
        }
    } else {
        // ---- max coordinate + zero bucket counters AND the ticket counter --
        if (t < NBLK + 1) counts[t] = 0;           // counts[0..63] + done
        float m = -3.0e38f;
        for (int i = t; i < NB * 4; i += 256) m = fmaxf(m, boxes[i]);
        for (int o = 32; o > 0; o >>= 1) m = fmaxf(m, __shfl_down(m, o));
        if ((t & 63) == 0) red[t >> 6] = m;
        __syncthreads();
        if (t == 0) *maxc = fmaxf(fmaxf(red[0], red[1]), fmaxf(red[2], red[3]));
    }
}

// =============== edge extraction + last-block greedy scan + pred =============
// Blocks 0..519: 4 waves x 1 triangle tile each (wave-synchronous LDS tiles).
// Ticket after release fence; the block drawing ticket EBLK-1 acquires and
// runs the verified serial scan + 4-wave epilogue.
// Blocks 520..583: pred boxes + centerness (independent of NMS).
__global__ void __launch_bounds__(256) edgescan_kernel(
        const float* __restrict__ boxes, const int* __restrict__ cls,
        const float* __restrict__ maxc, const int* __restrict__ sidx,
        int* __restrict__ counts, uint4* __restrict__ entries,
        u64* __restrict__ dcol,
        const float* __restrict__ loc, const float* __restrict__ deltas,
        const int* __restrict__ stride_p, float* __restrict__ pred_out,
        float* __restrict__ keep_out) {
    const int blk = blockIdx.x;
    const int t = threadIdx.x;
    const int wave = t >> 6, lane = t & 63;

    if (blk >= EBLK) {
        // ---------------- pred boxes + centerness ---------------------------
        int i = (blk - EBLK) * 256 + t;
        float s = (float)stride_p[0];
        float2 p = ((const float2*)loc)[i];
        float4 d = ((const float4*)deltas)[i];
        float c0 = fmaxf(d.x, 0.f), c1 = fmaxf(d.y, 0.f);
        float c2 = fmaxf(d.z, 0.f), c3 = fmaxf(d.w, 0.f);
        float b0 = p.x - c0 * s;
        float b1 = p.y - c1 * s;
        float b2 = p.x + c2 * s;
        float b3 = p.y + c3 * s;
        float lr_min = fminf(d.x, d.z), tb_min = fminf(d.y, d.w);
        float lr_max = fmaxf(d.x, d.z), tb_max = fmaxf(d.y, d.w);
        float cent = sqrtf((lr_min * tb_min) / (lr_max * tb_max));
        if (d.x == -1.f && d.y == -1.f && d.z == -1.f && d.w == -1.f) cent = -1.f;
        float* o = pred_out + (size_t)i * 5;
        o[0] = b0; o[1] = b1; o[2] = b2; o[3] = b3; o[4] = cent;
        return;
    }

    __shared__ float4 cbs[4][64];       // per-wave column tiles
    __shared__ float cas[4][64];
    __shared__ u64 rem_lds[NBLK];       // scanner state (last block only)
    __shared__ u64 kept_lds[NBLK];
    __shared__ int last_flag;
    int* done = counts + NBLK;          // ticket counter (zeroed by front)

    // ---------------- edge tile: tile = blk*4 + wave ------------------------
    {
        int idx = blk * 4 + wave, r = 0;
        while (idx >= NBLK - r) { idx -= NBLK - r; ++r; }
        int c = r + idx;
        float mc1 = maxc[0] + 1.0f;
        float4* cb = cbs[wave];
        float* ca = cas[wave];

        // gather row-tile box (sorted order) for this lane
        int jr = sidx[r * 64 + lane];
        float offr = (float)cls[jr] * mc1;
        float4 rb = ((const float4*)boxes)[jr];
        rb.x += offr; rb.y += offr; rb.z += offr; rb.w += offr;
        float ra = (rb.z - rb.x) * (rb.w - rb.y);

        // column tile into wave-local LDS (in-order DS pipe: no barrier)
        if (c == r) {
            cb[lane] = rb; ca[lane] = ra;
        } else {
            int jc = sidx[c * 64 + lane];
            float offc = (float)cls[jc] * mc1;
            float4 b = ((const float4*)boxes)[jc];
            b.x += offc; b.y += offc; b.z += offc; b.w += offc;
            cb[lane] = b; ca[lane] = (b.z - b.x) * (b.w - b.y);
        }

        u64 w = 0;
#pragma unroll 8
        for (int j = 0; j < 64; ++j) {
            float4 b = cb[j];
            float xi = fminf(rb.z, b.z) - fmaxf(rb.x, b.x);
            float yi = fminf(rb.w, b.w) - fmaxf(rb.y, b.y);
            float inter = fmaxf(xi, 0.f) * fmaxf(yi, 0.f);
            float iou = inter / (ra + ca[j] - inter);
            w |= (u64)(iou > IOU_THR) << j;
        }
        if (c == r) {
            w &= ~(1ull << lane);              // drop self-overlap bit
            dcol[r * 64 + lane] = w;           // dense diagonal word
        } else if (w) {
            int slot = atomicAdd(&counts[r], 1);
            if (slot < ECAP)
                entries[r * ECAP + slot] =
                    make_uint4((unsigned)(lane | (c << 8)), 0u,
                               (unsigned)(w & 0xffffffffull), (unsigned)(w >> 32));
        }
    }

    // ---------------- last-block ticket (release -> ticket) -----------------
    __syncthreads();
    if (t == 0) {
        __threadfence();                       // release: edges visible device-wide
        int tk = atomicAdd(done, 1);
        last_flag = (tk == EBLK - 1);
    }
    __syncthreads();
    if (!last_flag) return;
    __threadfence();                           // acquire: see all blocks' edges

    // ---------------- serial greedy scan (verified round-1 body) ------------
    if (t < 64) {
        rem_lds[t] = 0;
        int cnt_l = counts[t];
        u64 keptall_w = 0;
        u64 self = 1ull << t;
        uint4 cur = entries[t];                // depth-2 prefetch
        uint4 n1  = entries[ECAP + t];
        u64 cw_cur = dcol[t];
        u64 cw_n1  = dcol[64 + t];
        for (int b = 0; b < NBLK; ++b) {
            uint4 n2; u64 cw_n2;
            if (b < NBLK - 2) {
                n2    = entries[(u64)(b + 2) * ECAP + t];
                cw_n2 = dcol[(b + 2) * 64 + t];
            }
            int cnt = __builtin_amdgcn_readlane(cnt_l, b);
            if (cnt > ECAP) cnt = ECAP;

            u64 colw = self | cw_cur;          // dense diagonal table

            u64 rem = rem_lds[b];              // same-wave DS in-order
            u64 avail = ~rem;
            u64 edges = colw & avail & ~self;
            u64 involved = __ballot(edges != 0ull) & avail;
            u64 keptm = avail & ~involved;
            u64 sub = involved;
            while (sub) {
                int i = (int)__builtin_ctzll(sub);   // highest score first
                keptm |= 1ull << i;
                u64 ci = readlane64(colw, i);
                sub &= ~(ci | (1ull << i));
            }
            if (t == b) keptall_w = keptm;

            // lane-parallel merge: lane e holds entry e from prefetch
            if (t < cnt) {
                int l = cur.x & 255, c = cur.x >> 8;
                if ((keptm >> l) & 1ull)
                    atomicOr(&rem_lds[c], ((u64)cur.w << 32) | cur.z);
            }
            for (int e = 64; e < cnt; e += 64) {     // overflow (rare)
                int ee = e + t;
                if (ee < cnt) {
                    uint4 x = entries[(u64)b * ECAP + ee];
                    int l = x.x & 255, c = x.x >> 8;
                    if ((keptm >> l) & 1ull)
                        atomicOr(&rem_lds[c], ((u64)x.w << 32) | x.z);
                }
            }
            cur = n1; n1 = n2; cw_cur = cw_n1; cw_n1 = cw_n2;
        }
        kept_lds[t] = keptall_w;
    }
    __syncthreads();

    // epilogue: 4 waves x 16 iterations, scattered stores via sorted index
#pragma unroll
    for (int k = 0; k < 16; ++k) {
        int bb = wave + k * 4;
        u64 kw = kept_lds[bb];
        int idx = sidx[bb * 64 + lane];
        keep_out[idx] = ((kw >> lane) & 1ull) ? 1.0f : 0.0f;
    }
}

extern "C" void kernel_launch(void* const* d_in, const int* in_sizes, int n_in,
                              void* d_out, int out_size, void* d_ws, size_t ws_size,
                              hipStream_t stream) {
    const float* boxes   = (const float*)d_in[0];   // (4096,4)
    const float* scores  = (const float*)d_in[1];   // (4096,)
    const int*   cls     = (const int*)d_in[2];     // (4096,)
    const float* loc     = (const float*)d_in[3];   // (16384,2)
    const float* deltas  = (const float*)d_in[4];   // (16384,4)
    const int*   stride  = (const int*)d_in[5];     // scalar

    float* out = (float*)d_out;
    float* keep_out = out;          // 4096 floats (bool as 0/1)
    float* pred_out = out + NB;     // 16384*5 floats

    // workspace layout (16B-aligned pieces), ~1.08 MiB total
    char* ws = (char*)d_ws;
    float* maxc    = (float*)ws;                     ws += 16;
    int*   sidx    = (int*)ws;                       ws += NB * sizeof(int);
    int*   counts  = (int*)ws;                       ws += NBLK * sizeof(int) + 16; // +done
    uint4* entries = (uint4*)ws;                     ws += (size_t)NBLK * ECAP * sizeof(uint4);
    u64*   dcol    = (u64*)ws;                       // NBLK*64*8 B = 32 KiB

    front_kernel<<<RANKB + 1, 256, 0, stream>>>(boxes, scores, maxc, sidx, counts);
    edgescan_kernel<<<EBLK + PREDB, 256, 0, stream>>>(boxes, cls, maxc, sidx,
                                                      counts, entries, dcol,
                                                      loc, deltas, stride,
                                                      pred_out, keep_out);
}

// Round 4
// 102.774 us; speedup vs baseline: 1.7821x; 1.1292x over previous
//
#include <hip/hip_runtime.h>
#include <stdint.h>

#define NB 4096          // number of boxes
#define NBLK 64          // 64 blocks of 64 boxes
#define LLOC 16384       // number of locations
#define IOU_THR 0.5f
#define ECAP 1024        // entry capacity per source block bucket (global)
#define ESM  32          // per-block LDS entry cap in the scan (fast path)
#define RANKB 256        // rank blocks (16 boxes each)
#define NTRI (NBLK * (NBLK + 1) / 2)   // 2080 upper-triangle tiles

typedef unsigned long long u64;

__device__ __forceinline__ u64 readlane64(u64 v, int lane) {
    unsigned lo = (unsigned)__builtin_amdgcn_readlane((int)(unsigned)(v & 0xffffffffull), lane);
    unsigned hi = (unsigned)__builtin_amdgcn_readlane((int)(unsigned)(v >> 32), lane);
    return ((u64)hi << 32) | (u64)lo;
}

// ------- fused front: pred (0-63), rank (64-319, wave-per-box), maxc (320) ---
// (verbatim verified round-1 kernel)
__global__ void __launch_bounds__(256) fused_front(
        const float* __restrict__ boxes, const float* __restrict__ scores,
        const float* __restrict__ loc, const float* __restrict__ deltas,
        const int* __restrict__ stride_p,
        float* __restrict__ pred_out, float* __restrict__ maxc,
        int* __restrict__ sidx, int* __restrict__ counts) {
    __shared__ __align__(16) float sh[NB];
    __shared__ float red[4];
    int blk = blockIdx.x;
    int t = threadIdx.x;

    if (blk < 64) {
        // ---- pred boxes + centerness ----
        int i = blk * 256 + t;
        float s = (float)stride_p[0];
        float2 p = ((const float2*)loc)[i];
        float4 d = ((const float4*)deltas)[i];
        float c0 = fmaxf(d.x, 0.f), c1 = fmaxf(d.y, 0.f);
        float c2 = fmaxf(d.z, 0.f), c3 = fmaxf(d.w, 0.f);
        float b0 = p.x - c0 * s;
        float b1 = p.y - c1 * s;
        float b2 = p.x + c2 * s;
        float b3 = p.y + c3 * s;
        float lr_min = fminf(d.x, d.z), tb_min = fminf(d.y, d.w);
        float lr_max = fmaxf(d.x, d.z), tb_max = fmaxf(d.y, d.w);
        float cent = sqrtf((lr_min * tb_min) / (lr_max * tb_max));
        if (d.x == -1.f && d.y == -1.f && d.z == -1.f && d.w == -1.f) cent = -1.f;
        float* o = pred_out + (size_t)i * 5;
        o[0] = b0; o[1] = b1; o[2] = b2; o[3] = b3; o[4] = cent;
    } else if (blk < 64 + RANKB) {
        // ---- rank: one wave per box, 4 boxes/wave, 64-iteration j-loop ----
        for (int i = t; i < NB; i += 256) sh[i] = scores[i];
        __syncthreads();
        int wave = t >> 6, lane = t & 63;
        int base = (blk - 64) * 16 + wave * 4;     // 4 consecutive boxes
        float my0 = sh[base + 0], my1 = sh[base + 1];
        float my2 = sh[base + 2], my3 = sh[base + 3];
        int c0 = 0, c1 = 0, c2 = 0, c3 = 0;
#pragma unroll 8
        for (int k = 0; k < 64; ++k) {
            int j = lane + k * 64;                 // 2-way LDS bank alias: free
            float sj = sh[j];
            c0 += (sj > my0) || (sj == my0 && j < base + 0);
            c1 += (sj > my1) || (sj == my1 && j < base + 1);
            c2 += (sj > my2) || (sj == my2 && j < base + 2);
            c3 += (sj > my3) || (sj == my3 && j < base + 3);
        }
        for (int o = 32; o > 0; o >>= 1) {
            c0 += __shfl_down(c0, o); c1 += __shfl_down(c1, o);
            c2 += __shfl_down(c2, o); c3 += __shfl_down(c3, o);
        }
        if (lane == 0) {
            sidx[c0] = base + 0; sidx[c1] = base + 1;
            sidx[c2] = base + 2; sidx[c3] = base + 3;
        }
    } else {
        // ---- max coordinate + zero bucket counters ----
        if (t < NBLK) counts[t] = 0;
        float m = -3.0e38f;
        for (int i = t; i < NB * 4; i += 256) m = fmaxf(m, boxes[i]);
        for (int o = 32; o > 0; o >>= 1) m = fmaxf(m, __shfl_down(m, o));
        if ((t & 63) == 0) red[t >> 6] = m;
        __syncthreads();
        if (t == 0) *maxc = fmaxf(fmaxf(red[0], red[1]), fmaxf(red[2], red[3]));
    }
}

// -------- sparse suppression-edge extraction, inline gather, triangular ------
// (verbatim verified round-1 kernel)
__global__ void __launch_bounds__(64) edge_kernel(
        const float* __restrict__ boxes, const int* __restrict__ cls,
        const float* __restrict__ maxc, const int* __restrict__ sidx,
        int* __restrict__ counts, uint4* __restrict__ entries,
        u64* __restrict__ dcol) {
    int idx = blockIdx.x, r = 0;
    while (idx >= NBLK - r) { idx -= NBLK - r; ++r; }
    int c = r + idx;

    __shared__ float4 cb[64];
    __shared__ float ca[64];
    int t = threadIdx.x;                // 64 threads = one wave
    float mc1 = maxc[0] + 1.0f;

    int jr = sidx[r * 64 + t];
    float offr = (float)cls[jr] * mc1;
    float4 rb = ((const float4*)boxes)[jr];
    rb.x += offr; rb.y += offr; rb.z += offr; rb.w += offr;
    float ra = (rb.z - rb.x) * (rb.w - rb.y);

    if (c == r) {
        cb[t] = rb; ca[t] = ra;
    } else {
        int jc = sidx[c * 64 + t];
        float offc = (float)cls[jc] * mc1;
        float4 b = ((const float4*)boxes)[jc];
        b.x += offc; b.y += offc; b.z += offc; b.w += offc;
        cb[t] = b; ca[t] = (b.z - b.x) * (b.w - b.y);
    }
    __syncthreads();

    u64 w = 0;
#pragma unroll 8
    for (int j = 0; j < 64; ++j) {
        float4 b = cb[j];
        float xi = fminf(rb.z, b.z) - fmaxf(rb.x, b.x);
        float yi = fminf(rb.w, b.w) - fmaxf(rb.y, b.y);
        float inter = fmaxf(xi, 0.f) * fmaxf(yi, 0.f);
        float iou = inter / (ra + ca[j] - inter);
        w |= (u64)(iou > IOU_THR) << j;
    }
    if (c == r) {
        w &= ~(1ull << t);              // drop self-overlap bit
        dcol[r * 64 + t] = w;           // dense diagonal word, written once
    } else if (w) {
        int slot = atomicAdd(&counts[r], 1);
        if (slot < ECAP)
            entries[r * ECAP + slot] =
                make_uint4((unsigned)(t | (c << 8)), 0u,
                           (unsigned)(w & 0xffffffffull), (unsigned)(w >> 32));
    }
}

// ---------------- serial greedy scan: LDS-resident working set ---------------
// Phase A: 4 waves batch-load dcol + compacted entries into LDS and each
// thread's epilogue sidx values into registers (all latency TLP-hidden).
// Serial phase (wave 0): zero global loads on the critical path.
__global__ void __launch_bounds__(256) scan_kernel(
        const int* __restrict__ counts, const uint4* __restrict__ entries,
        const u64* __restrict__ dcol, const int* __restrict__ sidx,
        float* __restrict__ keep_out) {
    __shared__ u64 dcol_lds[NBLK * 64];          // 32 KB: dense diagonal words
    __shared__ u64 eword[NBLK][ESM];             // 16 KB: entry suppression words
    __shared__ unsigned emeta[NBLK][ESM];        //  8 KB: entry l | c<<8
    __shared__ u64 rem_lds[NBLK];                // removed-mask per block
    __shared__ u64 kept_lds[NBLK];               // kept-mask per block
    const int t = threadIdx.x;
    const int wave = t >> 6, lane = t & 63;

    // ---- epilogue sidx values -> registers (issued first, used last) -------
    int sx[16];
#pragma unroll
    for (int k = 0; k < 16; ++k) sx[k] = sidx[(wave + k * 4) * 64 + lane];

    // ---- Phase A: parallel preload of the scan working set -----------------
    if (t < NBLK) rem_lds[t] = 0;
#pragma unroll
    for (int k = 0; k < 16; ++k)                 // dcol: 4096 u64, coalesced
        dcol_lds[k * 256 + t] = dcol[k * 256 + t];
    int cnt_l = (t < 64) ? counts[t] : 0;        // wave0 lane b: count of block b
#pragma unroll
    for (int b = wave; b < NBLK; b += 4) {       // 16 blocks per wave
        int cnt = counts[b];                     // wave-uniform -> scalar load
        if (cnt > ESM) cnt = ESM;
        if (lane < cnt) {
            uint4 x = entries[(u64)b * ECAP + lane];
            emeta[b][lane] = x.x;
            eword[b][lane] = ((u64)x.w << 32) | x.z;
        }
    }
    __syncthreads();

    // ---- serial greedy over 64 blocks (wave 0, all-LDS critical path) ------
    if (t < 64) {
        u64 keptall_w = 0;
        u64 self = 1ull << t;
        for (int b = 0; b < NBLK; ++b) {
            int cnt = __builtin_amdgcn_readlane(cnt_l, b);
            if (cnt > ECAP) cnt = ECAP;
            int cl = cnt < ESM ? cnt : ESM;

            u64 colw = self | dcol_lds[b * 64 + t];   // LDS read

            u64 rem = rem_lds[b];              // same-wave DS in-order
            u64 avail = ~rem;
            u64 edges = colw & avail & ~self;
            u64 involved = __ballot(edges != 0ull) & avail;
            u64 keptm = avail & ~involved;
            u64 sub = involved;
            while (sub) {
                int i = (int)__builtin_ctzll(sub);   // highest score first
                keptm |= 1ull << i;
                u64 ci = readlane64(colw, i);
                sub &= ~(ci | (1ull << i));
            }
            if (t == b) keptall_w = keptm;

            // lane-parallel merge from LDS-compacted entries
            if (t < cl) {
                unsigned m = emeta[b][t];
                int l = m & 255, c = (m >> 8) & 255;
                if ((keptm >> l) & 1ull)
                    atomicOr(&rem_lds[c], eword[b][t]);
            }
            for (int e = ESM; e < cnt; e += 64) {    // overflow path (rare)
                int ee = e + t;
                if (ee < cnt) {
                    uint4 x = entries[(u64)b * ECAP + ee];
                    int l = x.x & 255, c = x.x >> 8;
                    if ((keptm >> l) & 1ull)
                        atomicOr(&rem_lds[c], ((u64)x.w << 32) | x.z);
                }
            }
        }
        kept_lds[t] = keptall_w;
    }
    __syncthreads();

    // ---- epilogue: 4 waves x 16 iters, scattered stores via register sidx --
#pragma unroll
    for (int k = 0; k < 16; ++k) {
        int bb = wave + k * 4;
        u64 kw = kept_lds[bb];                   // LDS broadcast read
        keep_out[sx[k]] = ((kw >> lane) & 1ull) ? 1.0f : 0.0f;
    }
}

extern "C" void kernel_launch(void* const* d_in, const int* in_sizes, int n_in,
                              void* d_out, int out_size, void* d_ws, size_t ws_size,
                              hipStream_t stream) {
    const float* boxes   = (const float*)d_in[0];   // (4096,4)
    const float* scores  = (const float*)d_in[1];   // (4096,)
    const int*   cls     = (const int*)d_in[2];     // (4096,)
    const float* loc     = (const float*)d_in[3];   // (16384,2)
    const float* deltas  = (const float*)d_in[4];   // (16384,4)
    const int*   stride  = (const int*)d_in[5];     // scalar

    float* out = (float*)d_out;
    float* keep_out = out;          // 4096 floats (bool as 0/1)
    float* pred_out = out + NB;     // 16384*5 floats

    // workspace layout (16B-aligned pieces), ~1.08 MiB total
    char* ws = (char*)d_ws;
    float* maxc    = (float*)ws;                     ws += 16;
    int*   sidx    = (int*)ws;                       ws += NB * sizeof(int);
    int*   counts  = (int*)ws;                       ws += NBLK * sizeof(int) + 16;
    uint4* entries = (uint4*)ws;                     ws += (size_t)NBLK * ECAP * sizeof(uint4);
    u64*   dcol    = (u64*)ws;                       // NBLK*64*8 B = 32 KiB

    fused_front<<<64 + RANKB + 1, 256, 0, stream>>>(boxes, scores, loc, deltas, stride,
                                                    pred_out, maxc, sidx, counts);
    edge_kernel<<<NTRI, 64, 0, stream>>>(boxes, cls, maxc, sidx, counts, entries, dcol);
    scan_kernel<<<1, 256, 0, stream>>>(counts, entries, dcol, sidx, keep_out);
}